// Round 1
// baseline (98.714 us; speedup 1.0000x reference)
//
#include <hip/hip_runtime.h>
#include <math.h>

// Problem constants (match reference)
#define NF 256          // features
#define NB 64           // batch
#define M_CON 515       // 2N+3 constraints
static constexpr double EPS_Q  = 1e-4;
static constexpr double SIGMA  = 0.1;
static constexpr double CAPC   = 10.0;
static constexpr int    ITERS  = 20;

// Fast fp64 reciprocal: v_rcp_f64 seed + 1 NR step -> ~fp64 noise floor.
__device__ __forceinline__ double drcp(double x) {
    double r = __builtin_amdgcn_rcp(x);
    r = fma(r, fma(-x, r, 1.0), r);
    return r;
}
// Raw rcp (~2^-26 rel): ONLY for step-ratio denominators and alpha.
__device__ __forceinline__ double drcp_fast(double x) {
    return __builtin_amdgcn_rcp(x);
}

// DPP cross-lane for fp64: two 32-bit v_mov_b32 dpp + reassemble.
template <int CTRL>
__device__ __forceinline__ double dpp_d(double v) {
    const int lo = __builtin_amdgcn_update_dpp(0, __double2loint(v), CTRL, 0xF, 0xF, true);
    const int hi = __builtin_amdgcn_update_dpp(0, __double2hiint(v), CTRL, 0xF, 0xF, true);
    return __hiloint2double(hi, lo);
}
__device__ __forceinline__ double bcast63(double v) {
    const int lo = __builtin_amdgcn_readlane(__double2loint(v), 63);
    const int hi = __builtin_amdgcn_readlane(__double2hiint(v), 63);
    return __hiloint2double(hi, lo);
}
__device__ __forceinline__ double wave_red_sum(double v) {
    v += dpp_d<0x121>(v);   // row_ror:1
    v += dpp_d<0x122>(v);   // row_ror:2
    v += dpp_d<0x124>(v);   // row_ror:4
    v += dpp_d<0x128>(v);   // row_ror:8
    v += dpp_d<0x142>(v);   // row_bcast15
    v += dpp_d<0x143>(v);   // row_bcast31
    return bcast63(v);
}
__device__ __forceinline__ double wave_red_max_nn(double v) {
    v = fmax(v, dpp_d<0x121>(v));
    v = fmax(v, dpp_d<0x122>(v));
    v = fmax(v, dpp_d<0x124>(v));
    v = fmax(v, dpp_d<0x128>(v));
    v = fmax(v, dpp_d<0x142>(v));
    v = fmax(v, dpp_d<0x143>(v));
    return bcast63(v);
}

// TWO batch items per wave (grid = 32 blocks x 64 threads).
// Rationale: 64 single-wave blocks leave 1 wave/SIMD, zero TLP; measured
// ~4000 cyc/iter vs ~1700-cyc issue floor => ~60% dependency stalls
// (rcp_f64+NR chains, 6-level DPP reduction trees, serial 2x2 Schur algebra).
// Interleaving two independent per-item instruction streams in one wave
// fills those stalls. Per-item computation graph is bit-identical to the
// 1-item kernel (same ops, same drcp/drcp_fast placement), so the fp64
// trajectory and absmax are unchanged.
// Lane j owns features j, j+64, j+128, j+192 for BOTH items.
__global__ __launch_bounds__(64, 1)
void pdipm_kernel(const float* __restrict__ xin,
                  const int* __restrict__ male,
                  float* __restrict__ out) {
    const int b0 = blockIdx.x * 2;           // items b0, b0+1
    const int lane = threadIdx.x;

    double mf[4];                            // shared: constraint mask is item-independent
    double e[2][4], x[2][4];                 // e = -(EPS*x + p) tracked
    double s_lo[2][4], s_hi[2][4], z_lo[2][4], z_hi[2][4];
    double rs_lo[2][4], rs_hi[2][4];
    double msum_p = 0.0;
    #pragma unroll
    for (int k = 0; k < 4; ++k) {
        const int f = lane + 64 * k;
        mf[k] = (double)male[f];
        msum_p += mf[k];
        #pragma unroll
        for (int i = 0; i < 2; ++i) {
            const double pv = -(double)xin[(b0 + i) * NF + f];
            e[i][k] = -pv;                    // x=0 -> e = -p
            x[i][k] = 0.0;
            s_lo[i][k] = 1.0; s_hi[i][k] = 1.0;
            z_lo[i][k] = 1.0; z_hi[i][k] = 1.0;
            rs_lo[i][k] = 1.0;                // s - x = 1
            rs_hi[i][k] = 0.0;                // s + x - 1 = 0
        }
    }
    const double nm = wave_red_sum(msum_p);
    const double rhs_fair = CAPC * nm * (1.0 / 256.0);

    // Scalar-constraint state (wave-uniform, per item).
    double s0[2], z0[2], sA[2], zA[2], sB[2], zB[2];
    double rs0[2], rsA[2], rsB[2], musum[2];
    #pragma unroll
    for (int i = 0; i < 2; ++i) {
        s0[i] = 1.0; z0[i] = 1.0; sA[i] = 1.0; zA[i] = 1.0; sB[i] = 1.0; zB[i] = 1.0;
        rs0[i] = 1.0 - CAPC;                  // s0 + 0 - C
        rsA[i] = -rhs_fair;                   // 1 + 0 - (rhs_fair+1)
        rsB[i] = 1.0 + rhs_fair;              // 1 - 0 + rhs_fair
        musum[i] = (double)M_CON;             // all s=z=1
    }

    for (int it = 0; it < ITERS; ++it) {
        double smu[2], i_s0[2], i_sA[2], i_sB[2], i_z0[2], i_zA[2], i_zB[2];
        double d0[2], dA[2], dB[2], beta[2], gamma[2], ia[2], ibb[2];
        #pragma unroll
        for (int i = 0; i < 2; ++i) {
            smu[i] = SIGMA * musum[i] * (1.0 / (double)M_CON);
            i_s0[i] = drcp(s0[i]); i_sA[i] = drcp(sA[i]); i_sB[i] = drcp(sB[i]);
            i_z0[i] = drcp_fast(z0[i]); i_zA[i] = drcp_fast(zA[i]); i_zB[i] = drcp_fast(zB[i]);
            d0[i] = z0[i] * i_s0[i]; dA[i] = zA[i] * i_sA[i]; dB[i] = zB[i] * i_sB[i];
            beta[i]  = d0[i] * rs0[i] + smu[i] * i_s0[i];
            gamma[i] = (dA[i] * rsA[i] + smu[i] * i_sA[i]) - (dB[i] * rsB[i] + smu[i] * i_sB[i]);
            ia[i]  = drcp(d0[i]);
            ibb[i] = drcp(dA[i] + dB[i]);
        }

        // ---- group 1: {s11, s12, t1, t2} ----
        // (i_zlo/i_zhi moved to group 2: ratio-only values; 2-item interleave
        //  already hides latency, and this cuts 64 VGPRs of live range.)
        double i_slo[2][4], i_shi[2][4];
        double d_lo[2][4], d_hi[2][4], invD[2][4], y[2][4];
        double s11_p[2] = {0.0, 0.0}, s12_p[2] = {0.0, 0.0};
        double t1_p[2]  = {0.0, 0.0}, t2_p[2]  = {0.0, 0.0};
        #pragma unroll
        for (int k = 0; k < 4; ++k) {
            #pragma unroll
            for (int i = 0; i < 2; ++i) {
                i_slo[i][k] = drcp(s_lo[i][k]);
                i_shi[i][k] = drcp(s_hi[i][k]);
                d_lo[i][k] = z_lo[i][k] * i_slo[i][k];
                d_hi[i][k] = z_hi[i][k] * i_shi[i][k];
                invD[i][k] = drcp(EPS_Q + d_lo[i][k] + d_hi[i][k]);
                const double rhat = e[i][k] + d_lo[i][k] * rs_lo[i][k] - d_hi[i][k] * rs_hi[i][k]
                                  + smu[i] * (i_slo[i][k] - i_shi[i][k]);
                y[i][k] = rhat * invD[i][k];
                s11_p[i] += invD[i][k];
                s12_p[i] += mf[k] * invD[i][k];
                t1_p[i]  += y[i][k];
                t2_p[i]  += mf[k] * y[i][k];
            }
        }
        // 8 independent reduction trees -> DPP chains fully pipelined.
        double s11[2], s12[2], t1[2], t2[2];
        #pragma unroll
        for (int i = 0; i < 2; ++i) {
            s11[i] = wave_red_sum(s11_p[i]);
            s12[i] = wave_red_sum(s12_p[i]);   // == s22 since m is 0/1
            t1[i]  = wave_red_sum(t1_p[i]);
            t2[i]  = wave_red_sum(t2_p[i]);
        }

        // ---- 2x2 capacitance algebra + scalar directions (per item) ----
        double C1[2], C2[2], C1pC2[2];
        double ds0[2], dsA[2], dsB[2], dz0[2], dzA[2], dzB[2];
        #pragma unroll
        for (int i = 0; i < 2; ++i) {
            const double k11 = ia[i] + s11[i];
            const double k22 = ibb[i] + s12[i];
            const double i_det = drcp(k11 * k22 - s12[i] * s12[i]);
            const double c1 = (k22 * t1[i] - s12[i] * t2[i]) * i_det;
            const double c2 = (k11 * t2[i] - s12[i] * t1[i]) * i_det;
            const double a1 =  ia[i] * k22 * i_det;
            const double a2 = -ia[i] * s12[i] * i_det;
            const double b1 = -ibb[i] * s12[i] * i_det;
            const double b2 =  ibb[i] * k11 * i_det;
            C1[i] = c1 + beta[i] * a1 + gamma[i] * b1;
            C2[i] = c2 + beta[i] * a2 + gamma[i] * b2;
            C1pC2[i] = C1[i] + C2[i];

            const double Sdx  = t1[i] - C1[i] * s11[i] - C2[i] * s12[i];
            const double Smdx = t2[i] - C1pC2[i] * s12[i];
            ds0[i] = -rs0[i] - Sdx;
            dsA[i] = -rsA[i] - Smdx;
            dsB[i] = -rsB[i] + Smdx;
            dz0[i] = smu[i] * i_s0[i] - z0[i] - d0[i] * ds0[i];
            dzA[i] = smu[i] * i_sA[i] - zA[i] - dA[i] * dsA[i];
            dzB[i] = smu[i] * i_sB[i] - zB[i] - dB[i] * dsB[i];
        }

        // ---- group 2: per-feature directions, {Sdsdz, rmax} ----
        double dx[2][4], ds_lo[2][4], ds_hi[2][4], dz_lo[2][4], dz_hi[2][4];
        double dsdz_p[2] = {0.0, 0.0};
        double rmax_p[2] = {0.0, 0.0};
        #pragma unroll
        for (int k = 0; k < 4; ++k) {
            #pragma unroll
            for (int i = 0; i < 2; ++i) {
                const double C12 = (mf[k] != 0.0) ? C1pC2[i] : C1[i];
                dx[i][k] = fma(-invD[i][k], C12, y[i][k]);
                ds_lo[i][k] = dx[i][k] - rs_lo[i][k];        // ds = -rs - G dx
                ds_hi[i][k] = -dx[i][k] - rs_hi[i][k];
                dz_lo[i][k] = smu[i] * i_slo[i][k] - z_lo[i][k] - d_lo[i][k] * ds_lo[i][k];
                dz_hi[i][k] = smu[i] * i_shi[i][k] - z_hi[i][k] - d_hi[i][k] * ds_hi[i][k];
                dsdz_p[i] += ds_lo[i][k] * dz_lo[i][k] + ds_hi[i][k] * dz_hi[i][k];
                const double i_zlo = drcp_fast(z_lo[i][k]);  // ratio-only
                const double i_zhi = drcp_fast(z_hi[i][k]);
                const double q1 = -ds_lo[i][k] * i_slo[i][k];
                const double q2 = -ds_hi[i][k] * i_shi[i][k];
                const double q3 = -dz_lo[i][k] * i_zlo;
                const double q4 = -dz_hi[i][k] * i_zhi;
                rmax_p[i] = fmax(rmax_p[i], fmax(fmax(q1, q2), fmax(q3, q4)));
            }
        }

        double Sdsdz[2], alpha[2], omA[2];
        #pragma unroll
        for (int i = 0; i < 2; ++i) {
            const double Sdsdz_w = wave_red_sum(dsdz_p[i]);
            double rmax = wave_red_max_nn(rmax_p[i]);
            rmax = fmax(rmax, fmax(-ds0[i] * i_s0[i], -dz0[i] * i_z0[i]));
            rmax = fmax(rmax, fmax(-dsA[i] * i_sA[i], -dzA[i] * i_zA[i]));
            rmax = fmax(rmax, fmax(-dsB[i] * i_sB[i], -dzB[i] * i_zB[i]));
            Sdsdz[i] = Sdsdz_w + ds0[i] * dz0[i] + dsA[i] * dzA[i] + dsB[i] * dzB[i];
            alpha[i] = fmin(1.0, 0.99 * drcp_fast(fmax(rmax, 0.99)));
            omA[i] = 1.0 - alpha[i];
        }

        // ---- state update (identities keep rs/musum exact) ----
        #pragma unroll
        for (int k = 0; k < 4; ++k) {
            #pragma unroll
            for (int i = 0; i < 2; ++i) {
                const double adx = alpha[i] * dx[i][k];
                x[i][k] += adx;
                e[i][k] = fma(-EPS_Q, adx, e[i][k]);
                s_lo[i][k] = fma(alpha[i], ds_lo[i][k], s_lo[i][k]);
                s_hi[i][k] = fma(alpha[i], ds_hi[i][k], s_hi[i][k]);
                z_lo[i][k] = fma(alpha[i], dz_lo[i][k], z_lo[i][k]);
                z_hi[i][k] = fma(alpha[i], dz_hi[i][k], z_hi[i][k]);
                rs_lo[i][k] *= omA[i];
                rs_hi[i][k] *= omA[i];
            }
        }
        #pragma unroll
        for (int i = 0; i < 2; ++i) {
            s0[i] = fma(alpha[i], ds0[i], s0[i]); z0[i] = fma(alpha[i], dz0[i], z0[i]);
            sA[i] = fma(alpha[i], dsA[i], sA[i]); zA[i] = fma(alpha[i], dzA[i], zA[i]);
            sB[i] = fma(alpha[i], dsB[i], sB[i]); zB[i] = fma(alpha[i], dzB[i], zB[i]);
            rs0[i] *= omA[i]; rsA[i] *= omA[i]; rsB[i] *= omA[i];
            musum[i] = musum[i] * (1.0 - alpha[i] * (1.0 - SIGMA))
                     + alpha[i] * alpha[i] * Sdsdz[i];
        }
    }

    #pragma unroll
    for (int k = 0; k < 4; ++k)
        #pragma unroll
        for (int i = 0; i < 2; ++i)
            out[(b0 + i) * NF + lane + 64 * k] = (float)x[i][k];
}

extern "C" void kernel_launch(void* const* d_in, const int* in_sizes, int n_in,
                              void* d_out, int out_size, void* d_ws, size_t ws_size,
                              hipStream_t stream) {
    const float* xin  = (const float*)d_in[0];   // [64, 256] fp32
    const int*   male = (const int*)d_in[1];     // [256] int32
    float* out = (float*)d_out;                  // [64, 256] fp32
    pdipm_kernel<<<NB / 2, 64, 0, stream>>>(xin, male, out);
}

// Round 2
// 72.464 us; speedup vs baseline: 1.3622x; 1.3622x over previous
//
#include <hip/hip_runtime.h>
#include <math.h>

// Problem constants (match reference)
#define NF 256          // features
#define NB 64           // batch
#define M_CON 515       // 2N+3 constraints
static constexpr double EPS_Q  = 1e-4;
static constexpr double SIGMA  = 0.1;
static constexpr double CAPC   = 10.0;
static constexpr int    ITERS  = 20;

// Fast fp64 reciprocal: v_rcp_f64 seed + 1 NR step -> ~fp64 noise floor.
__device__ __forceinline__ double drcp(double x) {
    double r = __builtin_amdgcn_rcp(x);
    r = fma(r, fma(-x, r, 1.0), r);
    return r;
}
// Raw rcp (~2^-26 rel): ONLY for step-ratio denominators and alpha.
__device__ __forceinline__ double drcp_fast(double x) {
    return __builtin_amdgcn_rcp(x);
}

// DPP cross-lane for fp64: two 32-bit v_mov_b32 dpp + reassemble.
template <int CTRL>
__device__ __forceinline__ double dpp_d(double v) {
    const int lo = __builtin_amdgcn_update_dpp(0, __double2loint(v), CTRL, 0xF, 0xF, true);
    const int hi = __builtin_amdgcn_update_dpp(0, __double2hiint(v), CTRL, 0xF, 0xF, true);
    return __hiloint2double(hi, lo);
}
// Wave sum/max: result valid in LANE 63 ONLY (lane 63 writes it to LDS for
// the cross-wave combine — no bcast63/readlane needed anymore).
__device__ __forceinline__ double wave_sum_l63(double v) {
    v += dpp_d<0x121>(v);   // row_ror:1
    v += dpp_d<0x122>(v);   // row_ror:2
    v += dpp_d<0x124>(v);   // row_ror:4
    v += dpp_d<0x128>(v);   // row_ror:8
    v += dpp_d<0x142>(v);   // row_bcast15
    v += dpp_d<0x143>(v);   // row_bcast31
    return v;
}
__device__ __forceinline__ double wave_max_nn_l63(double v) {
    v = fmax(v, dpp_d<0x121>(v));
    v = fmax(v, dpp_d<0x122>(v));
    v = fmax(v, dpp_d<0x124>(v));
    v = fmax(v, dpp_d<0x128>(v));
    v = fmax(v, dpp_d<0x142>(v));
    v = fmax(v, dpp_d<0x143>(v));
    return v;
}

// ONE item per BLOCK, 4 waves per block, 1 feature per lane (tid == feature).
// Rationale (round-1 post-mortem): wall time == one wave's serial 20-iter
// chain (64 items, 256 CUs -> all waves concurrent). So spend idle hardware
// to SHORTEN the chain: 4-way feature-split cuts per-wave issue ~4x on the
// feature-parallel phases; cross-wave combine = lane63 DPP partial -> LDS ->
// barrier -> 4-term sum. Two barriers/iter suffice: iter n's group-2 barrier
// orders iter n's red1 reads before iter n+1's red1 writes (and vice versa
// for red2), so no double-buffering.
// Bit-identical simplifications vs the 73us kernel:
//  * rs_hi == 0 for the whole trajectory (init 0, only op is *= (1-alpha))
//    -> all rs_hi terms removed exactly.
//  * rs_lo[k] identical across k (same init, same scalar multiplier)
//    -> single scalar rs_l.
__global__ __launch_bounds__(256, 1)
void pdipm_kernel(const float* __restrict__ xin,
                  const int* __restrict__ male,
                  float* __restrict__ out) {
    const int b = blockIdx.x;
    const int tid = threadIdx.x;      // == feature index (0..255)
    const int lane = tid & 63;
    const int w = tid >> 6;

    __shared__ double red1[4][4];     // [quantity][wave] : s11,s12,t1,t2 partials
    __shared__ double red2[2][4];     // [quantity][wave] : Sdsdz, rmax partials

    const double mf = (double)male[tid];
    double e = (double)xin[b * NF + tid];   // e = -(EPS*x+p), x=0 -> e = -p = xin
    double x = 0.0;
    double s_lo = 1.0, s_hi = 1.0, z_lo = 1.0, z_hi = 1.0;
    double rs_l = 1.0;                       // rs_lo scalar (s - x = 1)

    // one-time: nm = sum(mf) over all 256 features
    {
        const double v = wave_sum_l63(mf);
        if (lane == 63) red1[0][w] = v;
    }
    __syncthreads();
    const double nm = (red1[0][0] + red1[0][1]) + (red1[0][2] + red1[0][3]);
    __syncthreads();                          // protect red1 before iter-0 writes
    const double rhs_fair = CAPC * nm * (1.0 / 256.0);

    // Scalar-constraint state (wave-uniform).
    double s0 = 1.0, z0 = 1.0, sA = 1.0, zA = 1.0, sB = 1.0, zB = 1.0;
    double rs0 = 1.0 - CAPC;                  // s0 + 0 - C
    double rsA = -rhs_fair;                   // 1 + 0 - (rhs_fair+1)
    double rsB = 1.0 + rhs_fair;              // 1 - 0 + rhs_fair
    double musum = (double)M_CON;             // all s=z=1

    for (int it = 0; it < ITERS; ++it) {
        const double smu = SIGMA * musum * (1.0 / (double)M_CON);

        // ---- wave-uniform scalar precompute (overlaps group1) ----
        const double i_s0 = drcp(s0), i_sA = drcp(sA), i_sB = drcp(sB);
        const double i_z0 = drcp_fast(z0), i_zA = drcp_fast(zA), i_zB = drcp_fast(zB);
        const double d0 = z0 * i_s0, dA = zA * i_sA, dB = zB * i_sB;
        const double beta  = d0 * rs0 + smu * i_s0;
        const double gamma = (dA * rsA + smu * i_sA) - (dB * rsB + smu * i_sB);
        const double ia  = drcp(d0);
        const double ibb = drcp(dA + dB);

        // ---- group 1: per-feature (1 feature/lane) ----
        const double i_slo = drcp(s_lo);
        const double i_shi = drcp(s_hi);
        const double d_lo = z_lo * i_slo;
        const double d_hi = z_hi * i_shi;
        const double invD = drcp(EPS_Q + d_lo + d_hi);
        const double rhat = e + d_lo * rs_l + smu * (i_slo - i_shi);
        const double y = rhat * invD;

        // 4 reductions: wave DPP tree -> lane63 -> LDS -> 4-term combine
        const double p0 = wave_sum_l63(invD);
        const double p1 = wave_sum_l63(mf * invD);
        const double p2 = wave_sum_l63(y);
        const double p3 = wave_sum_l63(mf * y);
        if (lane == 63) {
            red1[0][w] = p0; red1[1][w] = p1; red1[2][w] = p2; red1[3][w] = p3;
        }
        __syncthreads();
        const double s11 = (red1[0][0] + red1[0][1]) + (red1[0][2] + red1[0][3]);
        const double s12 = (red1[1][0] + red1[1][1]) + (red1[1][2] + red1[1][3]);
        const double t1  = (red1[2][0] + red1[2][1]) + (red1[2][2] + red1[2][3]);
        const double t2  = (red1[3][0] + red1[3][1]) + (red1[3][2] + red1[3][3]);

        // ---- 2x2 capacitance algebra (closed-form M^-1 1 / M^-1 m) ----
        const double k11 = ia + s11;
        const double k22 = ibb + s12;
        const double i_det = drcp(k11 * k22 - s12 * s12);
        const double c1 = (k22 * t1 - s12 * t2) * i_det;
        const double c2 = (k11 * t2 - s12 * t1) * i_det;
        const double a1 =  ia * k22 * i_det;
        const double a2 = -ia * s12 * i_det;
        const double b1 = -ibb * s12 * i_det;
        const double b2 =  ibb * k11 * i_det;
        const double C1 = c1 + beta * a1 + gamma * b1;
        const double C2 = c2 + beta * a2 + gamma * b2;
        const double C1pC2 = C1 + C2;

        // ---- Sdx/Smdx via identities (no reduction) ----
        const double Sdx  = t1 - C1 * s11 - C2 * s12;
        const double Smdx = t2 - C1pC2 * s12;
        const double ds0 = -rs0 - Sdx;
        const double dsA = -rsA - Smdx;
        const double dsB = -rsB + Smdx;
        const double dz0 = smu * i_s0 - z0 - d0 * ds0;
        const double dzA = smu * i_sA - zA - dA * dsA;
        const double dzB = smu * i_sB - zB - dB * dsB;

        // ---- group 2: per-feature directions ----
        const double C12 = (mf != 0.0) ? C1pC2 : C1;
        const double dx = fma(-invD, C12, y);
        const double ds_lo = dx - rs_l;            // ds = -rs - G dx, (G dx)_lo = -dx
        const double ds_hi = -dx;                  // rs_hi == 0 exactly
        const double dz_lo = smu * i_slo - z_lo - d_lo * ds_lo;
        const double dz_hi = smu * i_shi - z_hi - d_hi * ds_hi;
        const double dsdz_p = ds_lo * dz_lo + ds_hi * dz_hi;
        const double i_zlo = drcp_fast(z_lo);      // ratio-only
        const double i_zhi = drcp_fast(z_hi);
        const double q1 = -ds_lo * i_slo;
        const double q2 = -ds_hi * i_shi;
        const double q3 = -dz_lo * i_zlo;
        const double q4 = -dz_hi * i_zhi;
        const double rmax_p = fmax(0.0, fmax(fmax(q1, q2), fmax(q3, q4)));

        const double pp0 = wave_sum_l63(dsdz_p);
        const double pp1 = wave_max_nn_l63(rmax_p);
        if (lane == 63) { red2[0][w] = pp0; red2[1][w] = pp1; }
        __syncthreads();
        const double Sdsdz_w = (red2[0][0] + red2[0][1]) + (red2[0][2] + red2[0][3]);
        double rmax = fmax(fmax(red2[1][0], red2[1][1]),
                           fmax(red2[1][2], red2[1][3]));

        // scalar-constraint ratios (wave-uniform)
        rmax = fmax(rmax, fmax(-ds0 * i_s0, -dz0 * i_z0));
        rmax = fmax(rmax, fmax(-dsA * i_sA, -dzA * i_zA));
        rmax = fmax(rmax, fmax(-dsB * i_sB, -dzB * i_zB));
        const double Sdsdz = Sdsdz_w + ds0 * dz0 + dsA * dzA + dsB * dzB;

        const double alpha = fmin(1.0, 0.99 * drcp_fast(fmax(rmax, 0.99)));
        const double omA = 1.0 - alpha;

        // ---- state update (identities keep rs/musum exact) ----
        const double adx = alpha * dx;
        x += adx;
        e = fma(-EPS_Q, adx, e);
        s_lo = fma(alpha, ds_lo, s_lo);
        s_hi = fma(alpha, ds_hi, s_hi);
        z_lo = fma(alpha, dz_lo, z_lo);
        z_hi = fma(alpha, dz_hi, z_hi);
        rs_l *= omA;

        s0 = fma(alpha, ds0, s0); z0 = fma(alpha, dz0, z0);
        sA = fma(alpha, dsA, sA); zA = fma(alpha, dzA, zA);
        sB = fma(alpha, dsB, sB); zB = fma(alpha, dzB, zB);
        rs0 *= omA; rsA *= omA; rsB *= omA;
        musum = musum * (1.0 - alpha * (1.0 - SIGMA)) + alpha * alpha * Sdsdz;
    }

    out[b * NF + tid] = (float)x;
}

extern "C" void kernel_launch(void* const* d_in, const int* in_sizes, int n_in,
                              void* d_out, int out_size, void* d_ws, size_t ws_size,
                              hipStream_t stream) {
    const float* xin  = (const float*)d_in[0];   // [64, 256] fp32
    const int*   male = (const int*)d_in[1];     // [256] int32
    float* out = (float*)d_out;                  // [64, 256] fp32
    pdipm_kernel<<<NB, 256, 0, stream>>>(xin, male, out);
}